// Round 3
// baseline (209.204 us; speedup 1.0000x reference)
//
#include <hip/hip_runtime.h>
#include <hip/hip_fp16.h>
#include <math.h>

#define D 128
#define D4 32        // uints per fp8 row
#define AP 136       // padded LDS row stride (halves) for MFMA staging
#define AP8 144      // padded LDS row stride (bytes) for fp8 C staging (16B aligned)
#define NBUCK 512    // coarse dst-buckets
#define NT 512       // threads per block for CSR kernels
#define EPB 2048     // edges per pass1 block (782 blocks: pass1 is block-serial-latency bound)
#define BCAP2 4096   // per-bucket capacity (mean 3125, sd ~56 -> 17 sigma slack)

typedef _Float16 f16x8 __attribute__((ext_vector_type(8)));
typedef float f32x4 __attribute__((ext_vector_type(4)));
typedef float f32x2 __attribute__((ext_vector_type(2)));

// ---------------- weight prep (both) + bcnt zero: one dispatch ----------------

__global__ void prep_all_kernel(const float* __restrict__ W1, _Float16* __restrict__ Wt1,
                                const float* __restrict__ W2, _Float16* __restrict__ Wt2,
                                int* __restrict__ bcnt) {
    int t = threadIdx.x;
    if (blockIdx.x == 0) { bcnt[t] = 0; bcnt[256 + t] = 0; }
    int half = blockIdx.x & 63;
    const float* W = (blockIdx.x < 64) ? W1 : W2;
    _Float16* Wt   = (blockIdx.x < 64) ? Wt1 : Wt2;
    int i = half * 256 + t;      // i = k*128 + c
    int k = i >> 7, c = i & 127;
    Wt[c * 128 + k] = (_Float16)W[i];
}

// ---------------- CSR build: 2-level LDS counting sort, all stores wave-dense --------
// Pass 1: 512 threads, 512 buckets, EPB=2048 (14KB LDS). Block count 782 ~ 3/CU for a
// kernel whose duration is dominated by one block's serial latency (loads + LDS atomics
// + scan barriers). Magic division npb=98: M=171197, exact for d<186413.

__global__ __launch_bounds__(NT) void bucket_pass1(const int* __restrict__ src,
                                                   const int* __restrict__ dst,
                                                   int* __restrict__ bcnt,
                                                   unsigned* __restrict__ buckets,
                                                   int E, unsigned magicM) {
    __shared__ unsigned stage[EPB];  // 8KB
    __shared__ int lcnt[NBUCK], loff[NBUCK], gbase[NBUCK];  // 6KB

    int t = threadIdx.x;
    int base = blockIdx.x * EPB;
    int nblk = min(EPB, E - base);
    lcnt[t] = 0;
    __syncthreads();

    for (int i = t; i < nblk; i += NT) {
        unsigned d = (unsigned)dst[base + i];
        int b = (int)(((unsigned long long)d * magicM) >> 24);
        atomicAdd(&lcnt[b], 1);
    }
    __syncthreads();

    int v = lcnt[t];
    loff[t] = v;   // will become inclusive scan, then exclusive
    __syncthreads();
    for (int off = 1; off < NT; off <<= 1) {
        int x = (t >= off) ? loff[t - off] : 0;
        __syncthreads();
        loff[t] += x;
        __syncthreads();
    }
    int incl = loff[t];
    __syncthreads();
    loff[t] = incl - v;                        // exclusive
    gbase[t] = atomicAdd(&bcnt[t], v);         // global reservation per (block,bucket)
    lcnt[t] = 0;                               // reuse as cursor
    __syncthreads();

    for (int i = t; i < nblk; i += NT) {       // place into LDS, bucket-ordered
        unsigned s = (unsigned)src[base + i];
        unsigned d = (unsigned)dst[base + i];
        unsigned pk = (s << 16) | d;
        int b = (int)(((unsigned long long)d * magicM) >> 24);
        int p = atomicAdd(&lcnt[b], 1);
        stage[loff[b] + p] = pk;
    }
    __syncthreads();

    for (int i = t; i < nblk; i += NT) {       // dense copy-out
        unsigned pk = stage[i];
        int b = (int)(((unsigned long long)(pk & 0xffffu) * magicM) >> 24);
        int pos = gbase[b] + (i - loff[b]);
        if (pos < BCAP2) buckets[(size_t)b * BCAP2 + pos] = pk;
    }
}

// Pass 2: one 512-thread block per bucket. NEW: within each node's edge list, edges are
// partitioned by src half (src < mid first). row_mid[node] marks the split. This lets the
// agg kernels gather phase-A (lower 3.2MB of the fp8 table, fits 4MB per-XCD L2) then
// phase-B (upper 3.2MB) -- the 6.4MB table no longer thrashes L2.
__global__ __launch_bounds__(NT) void csr_pass2(const unsigned* __restrict__ buckets,
                                                const int* __restrict__ bcnt,
                                                int* __restrict__ row_ptr,
                                                int* __restrict__ row_mid,
                                                float* __restrict__ dis,
                                                unsigned short* __restrict__ col,
                                                int N, int npb, int E, int mid) {
    __shared__ int cnt[NT], cntA[NT], sc[NT], excl[NT], curA[NT], curB[NT];  // 12KB
    __shared__ unsigned short estage[BCAP2];                                  // 8KB

    int b = blockIdx.x;
    int t = threadIdx.x;

    int bv = min(bcnt[t], BCAP2);
    sc[t] = bv;
    __syncthreads();
    for (int off = 1; off < NT; off <<= 1) {
        int x = (t >= off) ? sc[t - off] : 0;
        __syncthreads();
        sc[t] += x;
        __syncthreads();
    }
    int base = sc[b] - min(bcnt[b], BCAP2);    // exclusive prefix at b (uniform read)
    if (b == 0 && t == 0) row_ptr[N] = E;
    __syncthreads();

    int lo = b * npb;
    int nn = min(npb, N - lo);
    int n = min(bcnt[b], BCAP2);
    const unsigned* bk = buckets + (size_t)b * BCAP2;

    cnt[t] = 0;
    cntA[t] = 0;
    __syncthreads();
    for (int i = t; i < n; i += NT) {
        unsigned pk = bk[i];
        int dl = (int)(pk & 0xffffu) - lo;
        atomicAdd(&cnt[dl], 1);
        if ((int)(pk >> 16) < mid) atomicAdd(&cntA[dl], 1);
    }
    __syncthreads();
    int v = cnt[t];
    sc[t] = v;
    __syncthreads();
    for (int off = 1; off < NT; off <<= 1) {
        int x = (t >= off) ? sc[t - off] : 0;
        __syncthreads();
        sc[t] += x;
        __syncthreads();
    }
    excl[t] = sc[t] - v;
    if (t < nn) {
        row_ptr[lo + t] = base + excl[t];
        row_mid[lo + t] = base + excl[t] + cntA[t];
        dis[lo + t] = rsqrtf((float)v + 1.0f);
    }
    curA[t] = 0;
    curB[t] = 0;
    __syncthreads();
    for (int i = t; i < n; i += NT) {
        unsigned pk = bk[i];
        int dl = (int)(pk & 0xffffu) - lo;
        int s = (int)(pk >> 16);
        int p;
        if (s < mid) p = excl[dl] + atomicAdd(&curA[dl], 1);
        else         p = excl[dl] + cntA[dl] + atomicAdd(&curB[dl], 1);
        estage[p] = (unsigned short)s;
    }
    __syncthreads();
    for (int i = t; i < n; i += NT) col[base + i] = estage[i];   // dense
}

// ---------------- MFMA GEMM variants: C_fp8[N x 128] = dis[row]*(A @ W) ----------------

#define GEMM_CORE                                                            \
    const uint4* Wt16 = (const uint4*)Wt;                                    \
    for (int i = t; i < 128 * 16; i += 256) {                                \
        int r = i >> 4, ch = i & 15;                                         \
        *(uint4*)&Ws[r * AP + ch * 8] = Wt16[i];                             \
    }                                                                        \
    __syncthreads();                                                         \
    int wave = t >> 6;                                                       \
    int lane = t & 63;                                                       \
    int m16 = lane & 15;                                                     \
    int quad = lane >> 4;                                                    \
    f32x4 acc[8];                                                            \
    for (int n = 0; n < 8; n++) acc[n] = (f32x4){0.f, 0.f, 0.f, 0.f};        \
    _Pragma("unroll")                                                        \
    for (int kc = 0; kc < 4; kc++) {                                         \
        f16x8 a = *(const f16x8*)&As[(wave * 16 + m16) * AP + kc * 32 + quad * 8]; \
        _Pragma("unroll")                                                    \
        for (int n = 0; n < 8; n++) {                                        \
            f16x8 bfrag = *(const f16x8*)&Ws[(n * 16 + m16) * AP + kc * 32 + quad * 8]; \
            acc[n] = __builtin_amdgcn_mfma_f32_16x16x32_f16(a, bfrag, acc[n], 0, 0, 0); \
        }                                                                    \
    }                                                                        \
    __syncthreads();                                                         \
    unsigned char* Cs8 = (unsigned char*)As;                                 \
    float dv[4];                                                             \
    _Pragma("unroll")                                                        \
    for (int r = 0; r < 4; r++) {                                            \
        int grow = row0 + wave * 16 + quad * 4 + r;                          \
        dv[r] = (grow < N) ? dis[grow] : 0.f;                                \
    }                                                                        \
    _Pragma("unroll")                                                        \
    for (int n = 0; n < 8; n++)                                              \
        _Pragma("unroll")                                                    \
        for (int r = 0; r < 4; r++) {                                        \
            float val = acc[n][r] * dv[r];                                   \
            int wq = __builtin_amdgcn_cvt_pk_fp8_f32(val, val, 0, false);    \
            Cs8[(wave * 16 + quad * 4 + r) * AP8 + n * 16 + m16] = (unsigned char)(wq & 0xff); \
        }                                                                    \
    __syncthreads();                                                         \
    uint4* C16 = (uint4*)C8;                                                 \
    for (int i = lane; i < 128; i += 64) {                                   \
        int r = i >> 3, ch = i & 7;                                          \
        int grow = row0 + wave * 16 + r;                                     \
        if (grow < N)                                                        \
            C16[(size_t)grow * 8 + ch] = *(const uint4*)&Cs8[(wave * 16 + r) * AP8 + ch * 16]; \
    }

__global__ __launch_bounds__(256) void gemm_f32a_fp8c(const float* __restrict__ A,
                                                      const _Float16* __restrict__ Wt,
                                                      const float* __restrict__ dis,
                                                      unsigned int* __restrict__ C8, int N) {
    __shared__ _Float16 As[64 * AP];
    __shared__ _Float16 Ws[128 * AP];
    int t = threadIdx.x;
    int row0 = blockIdx.x * 64;
    const float4* A4 = (const float4*)A;
    for (int i = t; i < 64 * 16; i += 256) {
        int r = i >> 4, ch = i & 15;
        uint4 v = make_uint4(0, 0, 0, 0);
        if (row0 + r < N) {
            float4 a0 = A4[(size_t)(row0 + r) * 32 + ch * 2];
            float4 a1 = A4[(size_t)(row0 + r) * 32 + ch * 2 + 1];
            __half2 h0 = __floats2half2_rn(a0.x, a0.y);
            __half2 h1 = __floats2half2_rn(a0.z, a0.w);
            __half2 h2 = __floats2half2_rn(a1.x, a1.y);
            __half2 h3 = __floats2half2_rn(a1.z, a1.w);
            v.x = *(unsigned*)&h0; v.y = *(unsigned*)&h1;
            v.z = *(unsigned*)&h2; v.w = *(unsigned*)&h3;
        }
        *(uint4*)&As[r * AP + ch * 8] = v;
    }
    GEMM_CORE
}

__global__ __launch_bounds__(256) void gemm_f16a_fp8c(const _Float16* __restrict__ A,
                                                      const _Float16* __restrict__ Wt,
                                                      const float* __restrict__ dis,
                                                      unsigned int* __restrict__ C8, int N) {
    __shared__ _Float16 As[64 * AP];
    __shared__ _Float16 Ws[128 * AP];
    int t = threadIdx.x;
    int row0 = blockIdx.x * 64;
    const uint4* A16 = (const uint4*)A;
    for (int i = t; i < 64 * 16; i += 256) {
        int r = i >> 4, ch = i & 15;
        uint4 v = make_uint4(0, 0, 0, 0);
        if (row0 + r < N) v = A16[(size_t)(row0 + r) * 16 + ch];
        *(uint4*)&As[r * AP + ch * 8] = v;
    }
    GEMM_CORE
}

// ---------------- Aggregation (pull, fp8 table = 1 line/edge, u16 col) ----------------
// Phase-split gather: edges sorted so src<mid come first (row_mid). Phase A touches only
// the lower 3.2MB of t8, phase B the upper 3.2MB -- each fits per-XCD L2 (4MB), unlike
// the full 6.4MB table (round-1 counters: 46.5MB HBM re-fetch per agg = L2 thrash).
// 8-deep unrolled gather (R8-proven: line-fetch-rate bound, ~20 outstanding lines/CU).
// No LDS, low VGPR -> high occupancy; do NOT fuse with LDS-heavy GEMM (round-1 lesson).

__device__ __forceinline__ void acc8(float4& a, unsigned int u) {
    f32x2 lo = __builtin_amdgcn_cvt_pk_f32_fp8((int)u, false);
    f32x2 hi = __builtin_amdgcn_cvt_pk_f32_fp8((int)u, true);
    a.x += lo[0]; a.y += lo[1]; a.z += hi[0]; a.w += hi[1];
}

#define AGG_RANGE(lo_, hi_)                                                     \
    for (int base = (lo_); base < (hi_); base += 32) {                          \
        int cnt = min(32, (hi_) - base);                                        \
        int myc = (base + lane < (hi_)) ? (int)col[base + lane] : 0;            \
        int j = 0;                                                              \
        for (; j + 8 <= cnt; j += 8) {                                          \
            int s0 = __shfl(myc, j + 0, 32); int s1 = __shfl(myc, j + 1, 32);   \
            int s2 = __shfl(myc, j + 2, 32); int s3 = __shfl(myc, j + 3, 32);   \
            int s4 = __shfl(myc, j + 4, 32); int s5 = __shfl(myc, j + 5, 32);   \
            int s6 = __shfl(myc, j + 6, 32); int s7 = __shfl(myc, j + 7, 32);   \
            unsigned int u0 = t8[(size_t)s0 * D4 + lane];                       \
            unsigned int u1 = t8[(size_t)s1 * D4 + lane];                       \
            unsigned int u2 = t8[(size_t)s2 * D4 + lane];                       \
            unsigned int u3 = t8[(size_t)s3 * D4 + lane];                       \
            unsigned int u4 = t8[(size_t)s4 * D4 + lane];                       \
            unsigned int u5 = t8[(size_t)s5 * D4 + lane];                       \
            unsigned int u6 = t8[(size_t)s6 * D4 + lane];                       \
            unsigned int u7 = t8[(size_t)s7 * D4 + lane];                       \
            acc8(acc, u0); acc8(acc, u1); acc8(acc, u2); acc8(acc, u3);         \
            acc8(acc, u4); acc8(acc, u5); acc8(acc, u6); acc8(acc, u7);         \
        }                                                                       \
        for (; j < cnt; j++) {                                                  \
            int s = __shfl(myc, j, 32);                                         \
            acc8(acc, t8[(size_t)s * D4 + lane]);                               \
        }                                                                       \
    }

#define AGG8_BODY                                                               \
    float4 acc = make_float4(0.f, 0.f, 0.f, 0.f);                               \
    acc8(acc, t8[(size_t)node * D4 + lane]); /* self term (pre-scaled) */       \
    int e0 = row_ptr[node], e1 = row_ptr[node + 1];                             \
    int em = row_mid[node];                                                     \
    AGG_RANGE(e0, em)    /* phase A: src < mid (lower table half) */            \
    AGG_RANGE(em, e1)    /* phase B: src >= mid (upper table half) */           \
    float di = dis[node];                                                       \
    float4 bb = ((const float4*)bias)[lane];                                    \
    float4 o;                                                                   \
    o.x = fmaxf(fmaf(di, acc.x, bb.x), 0.f);                                    \
    o.y = fmaxf(fmaf(di, acc.y, bb.y), 0.f);                                    \
    o.z = fmaxf(fmaf(di, acc.z, bb.z), 0.f);                                    \
    o.w = fmaxf(fmaf(di, acc.w, bb.w), 0.f);

// layer-1: writes x1 fp16 (feeds gemm2 A-operand)
__global__ void agg_fp8_kernel(const unsigned int* __restrict__ t8, const float* __restrict__ bias,
                               const int* __restrict__ row_ptr, const int* __restrict__ row_mid,
                               const unsigned short* __restrict__ col,
                               const float* __restrict__ dis, _Float16* __restrict__ xout, int N) {
    int t = threadIdx.x;
    int node = blockIdx.x * 8 + (t >> 5);
    int lane = t & 31;
    if (node >= N) return;
    AGG8_BODY
    __half2 q0 = __floats2half2_rn(o.x, o.y);
    __half2 q1 = __floats2half2_rn(o.z, o.w);
    uint2 u;
    u.x = *(unsigned int*)&q0;
    u.y = *(unsigned int*)&q1;
    ((uint2*)xout)[(size_t)node * D4 + lane] = u;
}

// layer-2: fused sigmoid head, one score per node
__global__ void agg_head_fp8_kernel(const unsigned int* __restrict__ t8, const float* __restrict__ bias,
                                    const int* __restrict__ row_ptr, const int* __restrict__ row_mid,
                                    const unsigned short* __restrict__ col,
                                    const float* __restrict__ dis,
                                    const float* __restrict__ head_w, const float* __restrict__ head_b,
                                    float* __restrict__ out, int N) {
    int t = threadIdx.x;
    int node = blockIdx.x * 8 + (t >> 5);
    int lane = t & 31;
    if (node >= N) return;
    AGG8_BODY
    float4 wv = ((const float4*)head_w)[lane];
    float s = o.x * wv.x + o.y * wv.y + o.z * wv.z + o.w * wv.w;
    for (int m = 1; m < 32; m <<= 1) s += __shfl_xor(s, m, 64);
    if (lane == 0) {
        float v = s + head_b[0];
        out[node] = 1.0f / (1.0f + expf(-v));
    }
}

// ---------------- launch ----------------

extern "C" void kernel_launch(void* const* d_in, const int* in_sizes, int n_in,
                              void* d_out, int out_size, void* d_ws, size_t ws_size,
                              hipStream_t stream) {
    const int*   edge   = (const int*)d_in[0];
    const float* emb    = (const float*)d_in[1];
    const float* W1     = (const float*)d_in[2];
    const float* b1     = (const float*)d_in[3];
    const float* W2     = (const float*)d_in[4];
    const float* b2     = (const float*)d_in[5];
    const float* head_w = (const float*)d_in[6];
    const float* head_b = (const float*)d_in[7];
    float* out = (float*)d_out;

    int E = in_sizes[0] / 2;
    int N = in_sizes[1] / D;
    const int* srcp = edge;
    const int* dstp = edge + E;

    char* w = (char*)d_ws;
    auto alloc = [&](size_t bytes) -> char* {
        char* p = w;
        w += (bytes + 15) & ~(size_t)15;
        return p;
    };
    unsigned int*   t8      = (unsigned int*)alloc((size_t)N * D);          // 6.4 MB fp8 table
    _Float16*       x1h     = (_Float16*)alloc((size_t)N * D * 2);          // 12.8 MB x1 fp16
    unsigned*       buckets = (unsigned*)alloc((size_t)NBUCK * BCAP2 * 4);  // 8 MB
    _Float16*       Wt1     = (_Float16*)alloc((size_t)D * D * 2);
    _Float16*       Wt2     = (_Float16*)alloc((size_t)D * D * 2);
    unsigned short* col     = (unsigned short*)alloc((size_t)E * 2);        // 3.2 MB
    int*            bcnt    = (int*)alloc(NBUCK * 4);
    int*            row_ptr = (int*)alloc((size_t)(N + 1) * 4);
    int*            row_mid = (int*)alloc((size_t)N * 4);
    float*          dis     = (float*)alloc((size_t)N * 4);

    int npb = (N + NBUCK - 1) / NBUCK;                     // nodes per bucket (98)
    unsigned magicM = (16777216u + (unsigned)npb - 1) / (unsigned)npb;  // exact for d<186413
    int mid = N / 2;                                       // src-half split point (25000)
    int gP1 = (E + EPB - 1) / EPB;                         // 782
    int gG = (N + 63) / 64;
    int gA = (N + 7) / 8;

    prep_all_kernel<<<128, 256, 0, stream>>>(W1, Wt1, W2, Wt2, bcnt);
    bucket_pass1<<<gP1, NT, 0, stream>>>(srcp, dstp, bcnt, buckets, E, magicM);
    csr_pass2<<<NBUCK, NT, 0, stream>>>(buckets, bcnt, row_ptr, row_mid, dis, col, N, npb, E, mid);

    gemm_f32a_fp8c<<<gG, 256, 0, stream>>>(emb, Wt1, dis, t8, N);                 // hs1 fp8
    agg_fp8_kernel<<<gA, 256, 0, stream>>>(t8, b1, row_ptr, row_mid, col, dis, x1h, N);
    gemm_f16a_fp8c<<<gG, 256, 0, stream>>>(x1h, Wt2, dis, t8, N);                 // hs2 fp8
    agg_head_fp8_kernel<<<gA, 256, 0, stream>>>(t8, b2, row_ptr, row_mid, col, dis,
                                                head_w, head_b, out, N);          // scores
}

// Round 4
// 197.588 us; speedup vs baseline: 1.0588x; 1.0588x over previous
//
#include <hip/hip_runtime.h>
#include <hip/hip_cooperative_groups.h>
#include <hip/hip_fp16.h>
#include <math.h>

namespace cg = cooperative_groups;

#define D 128
#define D4 32        // uints per fp8 row
#define AP 136       // padded LDS row stride (halves) for MFMA staging
#define AP8 144      // padded LDS row stride (bytes) for fp8 C staging (16B aligned)
#define NBUCK 512    // coarse dst-buckets
#define NT 512       // threads per block for CSR kernels
#define EPB 4096     // edges per pass1 block (round-2 proven; round-3's 2048 unproven)
#define BCAP2 4096   // per-bucket capacity (mean 3125, sd ~56 -> 17 sigma slack)

#define CU_COUNT 256
#define COOP_BPCU 8
#define COOP_BLOCKS (CU_COUNT * COOP_BPCU)   // 2048 persistent blocks

typedef _Float16 f16x8 __attribute__((ext_vector_type(8)));
typedef float f32x4 __attribute__((ext_vector_type(4)));
typedef float f32x2 __attribute__((ext_vector_type(2)));

// ---------------- weight prep (both) + bcnt zero: one dispatch ----------------

__global__ void prep_all_kernel(const float* __restrict__ W1, _Float16* __restrict__ Wt1,
                                const float* __restrict__ W2, _Float16* __restrict__ Wt2,
                                int* __restrict__ bcnt) {
    int t = threadIdx.x;
    if (blockIdx.x == 0) { bcnt[t] = 0; bcnt[256 + t] = 0; }
    int half = blockIdx.x & 63;
    const float* W = (blockIdx.x < 64) ? W1 : W2;
    _Float16* Wt   = (blockIdx.x < 64) ? Wt1 : Wt2;
    int i = half * 256 + t;      // i = k*128 + c
    int k = i >> 7, c = i & 127;
    Wt[c * 128 + k] = (_Float16)W[i];
}

// ---------------- CSR build: 2-level LDS counting sort, all stores wave-dense --------
// Pass 1: 512 threads, 512 buckets, EPB=4096 (22KB LDS), 391 blocks.
// Magic division npb=98: M=171197, exact for d<186413.

__global__ __launch_bounds__(NT) void bucket_pass1(const int* __restrict__ src,
                                                   const int* __restrict__ dst,
                                                   int* __restrict__ bcnt,
                                                   unsigned* __restrict__ buckets,
                                                   int E, unsigned magicM) {
    __shared__ unsigned stage[EPB];  // 16KB
    __shared__ int lcnt[NBUCK], loff[NBUCK], gbase[NBUCK];  // 6KB

    int t = threadIdx.x;
    int base = blockIdx.x * EPB;
    int nblk = min(EPB, E - base);
    lcnt[t] = 0;
    __syncthreads();

    for (int i = t; i < nblk; i += NT) {
        unsigned d = (unsigned)dst[base + i];
        int b = (int)(((unsigned long long)d * magicM) >> 24);
        atomicAdd(&lcnt[b], 1);
    }
    __syncthreads();

    int v = lcnt[t];
    loff[t] = v;   // will become inclusive scan, then exclusive
    __syncthreads();
    for (int off = 1; off < NT; off <<= 1) {
        int x = (t >= off) ? loff[t - off] : 0;
        __syncthreads();
        loff[t] += x;
        __syncthreads();
    }
    int incl = loff[t];
    __syncthreads();
    loff[t] = incl - v;                        // exclusive
    gbase[t] = atomicAdd(&bcnt[t], v);         // global reservation per (block,bucket)
    lcnt[t] = 0;                               // reuse as cursor
    __syncthreads();

    for (int i = t; i < nblk; i += NT) {       // place into LDS, bucket-ordered
        unsigned s = (unsigned)src[base + i];
        unsigned d = (unsigned)dst[base + i];
        unsigned pk = (s << 16) | d;
        int b = (int)(((unsigned long long)d * magicM) >> 24);
        int p = atomicAdd(&lcnt[b], 1);
        stage[loff[b] + p] = pk;
    }
    __syncthreads();

    for (int i = t; i < nblk; i += NT) {       // dense copy-out
        unsigned pk = stage[i];
        int b = (int)(((unsigned long long)(pk & 0xffffu) * magicM) >> 24);
        int pos = gbase[b] + (i - loff[b]);
        if (pos < BCAP2) buckets[(size_t)b * BCAP2 + pos] = pk;
    }
}

// Pass 2: one 512-thread block per bucket. Within each node's edge list, edges are
// partitioned by src half (src < mid first); row_mid[node] marks the split. The
// cooperative agg kernels use this for GRID-WIDE phase A/B (round-3 lesson: per-row
// phasing without global coordination gives no L2 locality).
__global__ __launch_bounds__(NT) void csr_pass2(const unsigned* __restrict__ buckets,
                                                const int* __restrict__ bcnt,
                                                int* __restrict__ row_ptr,
                                                int* __restrict__ row_mid,
                                                float* __restrict__ dis,
                                                unsigned short* __restrict__ col,
                                                int N, int npb, int E, int mid) {
    __shared__ int cnt[NT], cntA[NT], sc[NT], excl[NT], curB[NT];  // 10KB
    __shared__ unsigned short estage[BCAP2];                        // 8KB

    int b = blockIdx.x;
    int t = threadIdx.x;

    int bv = min(bcnt[t], BCAP2);
    sc[t] = bv;
    __syncthreads();
    for (int off = 1; off < NT; off <<= 1) {
        int x = (t >= off) ? sc[t - off] : 0;
        __syncthreads();
        sc[t] += x;
        __syncthreads();
    }
    int base = sc[b] - min(bcnt[b], BCAP2);    // exclusive prefix at b (uniform read)
    if (b == 0 && t == 0) row_ptr[N] = E;
    __syncthreads();

    int lo = b * npb;
    int nn = min(npb, N - lo);
    int n = min(bcnt[b], BCAP2);
    const unsigned* bk = buckets + (size_t)b * BCAP2;

    cnt[t] = 0;
    cntA[t] = 0;
    __syncthreads();
    for (int i = t; i < n; i += NT) {
        unsigned pk = bk[i];
        int dl = (int)(pk & 0xffffu) - lo;
        atomicAdd(&cnt[dl], 1);
        if ((int)(pk >> 16) < mid) atomicAdd(&cntA[dl], 1);
    }
    __syncthreads();
    int v = cnt[t];
    sc[t] = v;
    __syncthreads();
    for (int off = 1; off < NT; off <<= 1) {
        int x = (t >= off) ? sc[t - off] : 0;
        __syncthreads();
        sc[t] += x;
        __syncthreads();
    }
    excl[t] = sc[t] - v;
    if (t < nn) {
        row_ptr[lo + t] = base + excl[t];
        row_mid[lo + t] = base + excl[t] + cntA[t];
        dis[lo + t] = rsqrtf((float)v + 1.0f);
    }
    cnt[t] = 0;   // reuse as phase-A cursor
    curB[t] = 0;
    __syncthreads();
    for (int i = t; i < n; i += NT) {
        unsigned pk = bk[i];
        int dl = (int)(pk & 0xffffu) - lo;
        int s = (int)(pk >> 16);
        int p;
        if (s < mid) p = excl[dl] + atomicAdd(&cnt[dl], 1);
        else         p = excl[dl] + cntA[dl] + atomicAdd(&curB[dl], 1);
        estage[p] = (unsigned short)s;
    }
    __syncthreads();
    for (int i = t; i < n; i += NT) col[base + i] = estage[i];   // dense
}

// ---------------- MFMA GEMM variants: C_fp8[N x 128] = dis[row]*(A @ W) ----------------

#define GEMM_CORE                                                            \
    const uint4* Wt16 = (const uint4*)Wt;                                    \
    for (int i = t; i < 128 * 16; i += 256) {                                \
        int r = i >> 4, ch = i & 15;                                         \
        *(uint4*)&Ws[r * AP + ch * 8] = Wt16[i];                             \
    }                                                                        \
    __syncthreads();                                                         \
    int wave = t >> 6;                                                       \
    int lane = t & 63;                                                       \
    int m16 = lane & 15;                                                     \
    int quad = lane >> 4;                                                    \
    f32x4 acc[8];                                                            \
    for (int n = 0; n < 8; n++) acc[n] = (f32x4){0.f, 0.f, 0.f, 0.f};        \
    _Pragma("unroll")                                                        \
    for (int kc = 0; kc < 4; kc++) {                                         \
        f16x8 a = *(const f16x8*)&As[(wave * 16 + m16) * AP + kc * 32 + quad * 8]; \
        _Pragma("unroll")                                                    \
        for (int n = 0; n < 8; n++) {                                        \
            f16x8 bfrag = *(const f16x8*)&Ws[(n * 16 + m16) * AP + kc * 32 + quad * 8]; \
            acc[n] = __builtin_amdgcn_mfma_f32_16x16x32_f16(a, bfrag, acc[n], 0, 0, 0); \
        }                                                                    \
    }                                                                        \
    __syncthreads();                                                         \
    unsigned char* Cs8 = (unsigned char*)As;                                 \
    float dv[4];                                                             \
    _Pragma("unroll")                                                        \
    for (int r = 0; r < 4; r++) {                                            \
        int grow = row0 + wave * 16 + quad * 4 + r;                          \
        dv[r] = (grow < N) ? dis[grow] : 0.f;                                \
    }                                                                        \
    _Pragma("unroll")                                                        \
    for (int n = 0; n < 8; n++)                                              \
        _Pragma("unroll")                                                    \
        for (int r = 0; r < 4; r++) {                                        \
            float val = acc[n][r] * dv[r];                                   \
            int wq = __builtin_amdgcn_cvt_pk_fp8_f32(val, val, 0, false);    \
            Cs8[(wave * 16 + quad * 4 + r) * AP8 + n * 16 + m16] = (unsigned char)(wq & 0xff); \
        }                                                                    \
    __syncthreads();                                                         \
    uint4* C16 = (uint4*)C8;                                                 \
    for (int i = lane; i < 128; i += 64) {                                   \
        int r = i >> 3, ch = i & 7;                                          \
        int grow = row0 + wave * 16 + r;                                     \
        if (grow < N)                                                        \
            C16[(size_t)grow * 8 + ch] = *(const uint4*)&Cs8[(wave * 16 + r) * AP8 + ch * 16]; \
    }

__global__ __launch_bounds__(256) void gemm_f32a_fp8c(const float* __restrict__ A,
                                                      const _Float16* __restrict__ Wt,
                                                      const float* __restrict__ dis,
                                                      unsigned int* __restrict__ C8, int N) {
    __shared__ _Float16 As[64 * AP];
    __shared__ _Float16 Ws[128 * AP];
    int t = threadIdx.x;
    int row0 = blockIdx.x * 64;
    const float4* A4 = (const float4*)A;
    for (int i = t; i < 64 * 16; i += 256) {
        int r = i >> 4, ch = i & 15;
        uint4 v = make_uint4(0, 0, 0, 0);
        if (row0 + r < N) {
            float4 a0 = A4[(size_t)(row0 + r) * 32 + ch * 2];
            float4 a1 = A4[(size_t)(row0 + r) * 32 + ch * 2 + 1];
            __half2 h0 = __floats2half2_rn(a0.x, a0.y);
            __half2 h1 = __floats2half2_rn(a0.z, a0.w);
            __half2 h2 = __floats2half2_rn(a1.x, a1.y);
            __half2 h3 = __floats2half2_rn(a1.z, a1.w);
            v.x = *(unsigned*)&h0; v.y = *(unsigned*)&h1;
            v.z = *(unsigned*)&h2; v.w = *(unsigned*)&h3;
        }
        *(uint4*)&As[r * AP + ch * 8] = v;
    }
    GEMM_CORE
}

__global__ __launch_bounds__(256) void gemm_f16a_fp8c(const _Float16* __restrict__ A,
                                                      const _Float16* __restrict__ Wt,
                                                      const float* __restrict__ dis,
                                                      unsigned int* __restrict__ C8, int N) {
    __shared__ _Float16 As[64 * AP];
    __shared__ _Float16 Ws[128 * AP];
    int t = threadIdx.x;
    int row0 = blockIdx.x * 64;
    const uint4* A16 = (const uint4*)A;
    for (int i = t; i < 64 * 16; i += 256) {
        int r = i >> 4, ch = i & 15;
        uint4 v = make_uint4(0, 0, 0, 0);
        if (row0 + r < N) v = A16[(size_t)(row0 + r) * 16 + ch];
        *(uint4*)&As[r * AP + ch * 8] = v;
    }
    GEMM_CORE
}

// ---------------- Aggregation (pull, fp8 table = 1 line/edge, u16 col) ----------------
// 8-deep unrolled gather (line-fetch-rate bound). No fusion with LDS-heavy GEMM
// (round-1: occupancy 12 waves/CU -> 2.6x slower gather).

__device__ __forceinline__ void acc8(float4& a, unsigned int u) {
    f32x2 lo = __builtin_amdgcn_cvt_pk_f32_fp8((int)u, false);
    f32x2 hi = __builtin_amdgcn_cvt_pk_f32_fp8((int)u, true);
    a.x += lo[0]; a.y += lo[1]; a.z += hi[0]; a.w += hi[1];
}

#define AGG_RANGE(lo_, hi_)                                                     \
    for (int base = (lo_); base < (hi_); base += 32) {                          \
        int cnt = min(32, (hi_) - base);                                        \
        int myc = (base + lane < (hi_)) ? (int)col[base + lane] : 0;            \
        int j = 0;                                                              \
        for (; j + 8 <= cnt; j += 8) {                                          \
            int s0 = __shfl(myc, j + 0, 32); int s1 = __shfl(myc, j + 1, 32);   \
            int s2 = __shfl(myc, j + 2, 32); int s3 = __shfl(myc, j + 3, 32);   \
            int s4 = __shfl(myc, j + 4, 32); int s5 = __shfl(myc, j + 5, 32);   \
            int s6 = __shfl(myc, j + 6, 32); int s7 = __shfl(myc, j + 7, 32);   \
            unsigned int u0 = t8[(size_t)s0 * D4 + lane];                       \
            unsigned int u1 = t8[(size_t)s1 * D4 + lane];                       \
            unsigned int u2 = t8[(size_t)s2 * D4 + lane];                       \
            unsigned int u3 = t8[(size_t)s3 * D4 + lane];                       \
            unsigned int u4 = t8[(size_t)s4 * D4 + lane];                       \
            unsigned int u5 = t8[(size_t)s5 * D4 + lane];                       \
            unsigned int u6 = t8[(size_t)s6 * D4 + lane];                       \
            unsigned int u7 = t8[(size_t)s7 * D4 + lane];                       \
            acc8(acc, u0); acc8(acc, u1); acc8(acc, u2); acc8(acc, u3);         \
            acc8(acc, u4); acc8(acc, u5); acc8(acc, u6); acc8(acc, u7);         \
        }                                                                       \
        for (; j < cnt; j++) {                                                  \
            int s = __shfl(myc, j, 32);                                         \
            acc8(acc, t8[(size_t)s * D4 + lane]);                               \
        }                                                                       \
    }

#define AGG_EPILOGUE                                                            \
    float di = dis[node];                                                       \
    float4 bb = ((const float4*)bias)[lane];                                    \
    float4 o;                                                                   \
    o.x = fmaxf(fmaf(di, acc.x, bb.x), 0.f);                                    \
    o.y = fmaxf(fmaf(di, acc.y, bb.y), 0.f);                                    \
    o.z = fmaxf(fmaf(di, acc.z, bb.z), 0.f);                                    \
    o.w = fmaxf(fmaf(di, acc.w, bb.w), 0.f);

#define HEAD_EPILOGUE                                                           \
    float4 wv = ((const float4*)head_w)[lane];                                  \
    float s = o.x * wv.x + o.y * wv.y + o.z * wv.z + o.w * wv.w;                \
    for (int m = 1; m < 32; m <<= 1) s += __shfl_xor(s, m, 64);                 \
    if (lane == 0) {                                                            \
        float v = s + head_b[0];                                                \
        out[node] = 1.0f / (1.0f + expf(-v));                                   \
    }

#define X1_PACK_WRITE                                                           \
    __half2 q0 = __floats2half2_rn(o.x, o.y);                                   \
    __half2 q1 = __floats2half2_rn(o.z, o.w);                                   \
    uint2 u;                                                                    \
    u.x = *(unsigned int*)&q0;                                                  \
    u.y = *(unsigned int*)&q1;                                                  \
    ((uint2*)xout)[(size_t)node * D4 + lane] = u;

// ---- cooperative persistent variants: grid-wide phase A (src<mid) / phase B ----
// 2048 blocks x 256 thr, LDS 16KB, launch_bounds(256,8) -> VGPR<=64 so 8 blk/CU
// co-reside (cooperative residency requirement AND full gather occupancy).
// Phase A: whole machine gathers only from lower 3.2MB of t8 -> fits 4MB per-XCD L2.
// Accumulators park in LDS across grid.sync() (no partial-sum HBM round trip).

__global__ __launch_bounds__(256, 8) void agg1_coop(const unsigned int* __restrict__ t8,
                                                    const float* __restrict__ bias,
                                                    const int* __restrict__ row_ptr,
                                                    const int* __restrict__ row_mid,
                                                    const unsigned short* __restrict__ col,
                                                    const float* __restrict__ dis,
                                                    _Float16* __restrict__ xout,
                                                    int N, int npb, int mid) {
    __shared__ float4 accs[1024];   // up to 32 node-slots * 32 lanes, 16KB
    cg::grid_group gg = cg::this_grid();
    int t = threadIdx.x, slot = t >> 5, lane = t & 31;
    int nb = blockIdx.x * npb;
    int ngroups = (npb + 7) >> 3;
    for (int g = 0; g < ngroups; ++g) {
        int ln = g * 8 + slot;
        int node = nb + ln;
        float4 acc = make_float4(0.f, 0.f, 0.f, 0.f);
        if (ln < npb && node < N) {
            if (node < mid) acc8(acc, t8[(size_t)node * D4 + lane]);  // self, phase-pure
            int e0 = row_ptr[node], em = row_mid[node];
            AGG_RANGE(e0, em)
        }
        accs[ln * 32 + lane] = acc;
    }
    gg.sync();
    for (int g = 0; g < ngroups; ++g) {
        int ln = g * 8 + slot;
        int node = nb + ln;
        if (ln >= npb || node >= N) continue;
        float4 acc = accs[ln * 32 + lane];
        if (node >= mid) acc8(acc, t8[(size_t)node * D4 + lane]);
        int em = row_mid[node], e1 = row_ptr[node + 1];
        AGG_RANGE(em, e1)
        AGG_EPILOGUE
        X1_PACK_WRITE
    }
}

__global__ __launch_bounds__(256, 8) void agg_head_coop(const unsigned int* __restrict__ t8,
                                                        const float* __restrict__ bias,
                                                        const int* __restrict__ row_ptr,
                                                        const int* __restrict__ row_mid,
                                                        const unsigned short* __restrict__ col,
                                                        const float* __restrict__ dis,
                                                        const float* __restrict__ head_w,
                                                        const float* __restrict__ head_b,
                                                        float* __restrict__ out,
                                                        int N, int npb, int mid) {
    __shared__ float4 accs[1024];
    cg::grid_group gg = cg::this_grid();
    int t = threadIdx.x, slot = t >> 5, lane = t & 31;
    int nb = blockIdx.x * npb;
    int ngroups = (npb + 7) >> 3;
    for (int g = 0; g < ngroups; ++g) {
        int ln = g * 8 + slot;
        int node = nb + ln;
        float4 acc = make_float4(0.f, 0.f, 0.f, 0.f);
        if (ln < npb && node < N) {
            if (node < mid) acc8(acc, t8[(size_t)node * D4 + lane]);
            int e0 = row_ptr[node], em = row_mid[node];
            AGG_RANGE(e0, em)
        }
        accs[ln * 32 + lane] = acc;
    }
    gg.sync();
    for (int g = 0; g < ngroups; ++g) {
        int ln = g * 8 + slot;
        int node = nb + ln;
        if (ln >= npb || node >= N) continue;
        float4 acc = accs[ln * 32 + lane];
        if (node >= mid) acc8(acc, t8[(size_t)node * D4 + lane]);
        int em = row_mid[node], e1 = row_ptr[node + 1];
        AGG_RANGE(em, e1)
        AGG_EPILOGUE
        HEAD_EPILOGUE
    }
}

// ---- plain fallback variants (round-2 proven, single range) ----

__global__ void agg_fp8_kernel(const unsigned int* __restrict__ t8, const float* __restrict__ bias,
                               const int* __restrict__ row_ptr, const unsigned short* __restrict__ col,
                               const float* __restrict__ dis, _Float16* __restrict__ xout, int N) {
    int t = threadIdx.x;
    int node = blockIdx.x * 8 + (t >> 5);
    int lane = t & 31;
    if (node >= N) return;
    float4 acc = make_float4(0.f, 0.f, 0.f, 0.f);
    acc8(acc, t8[(size_t)node * D4 + lane]);
    int e0 = row_ptr[node], e1 = row_ptr[node + 1];
    AGG_RANGE(e0, e1)
    AGG_EPILOGUE
    X1_PACK_WRITE
}

__global__ void agg_head_fp8_kernel(const unsigned int* __restrict__ t8, const float* __restrict__ bias,
                                    const int* __restrict__ row_ptr, const unsigned short* __restrict__ col,
                                    const float* __restrict__ dis,
                                    const float* __restrict__ head_w, const float* __restrict__ head_b,
                                    float* __restrict__ out, int N) {
    int t = threadIdx.x;
    int node = blockIdx.x * 8 + (t >> 5);
    int lane = t & 31;
    if (node >= N) return;
    float4 acc = make_float4(0.f, 0.f, 0.f, 0.f);
    acc8(acc, t8[(size_t)node * D4 + lane]);
    int e0 = row_ptr[node], e1 = row_ptr[node + 1];
    AGG_RANGE(e0, e1)
    AGG_EPILOGUE
    HEAD_EPILOGUE
}

// ---------------- launch ----------------

extern "C" void kernel_launch(void* const* d_in, const int* in_sizes, int n_in,
                              void* d_out, int out_size, void* d_ws, size_t ws_size,
                              hipStream_t stream) {
    const int*   edge   = (const int*)d_in[0];
    const float* emb    = (const float*)d_in[1];
    const float* W1     = (const float*)d_in[2];
    const float* b1     = (const float*)d_in[3];
    const float* W2     = (const float*)d_in[4];
    const float* b2     = (const float*)d_in[5];
    const float* head_w = (const float*)d_in[6];
    const float* head_b = (const float*)d_in[7];
    float* out = (float*)d_out;

    int E = in_sizes[0] / 2;
    int N = in_sizes[1] / D;
    const int* srcp = edge;
    const int* dstp = edge + E;

    char* w = (char*)d_ws;
    auto alloc = [&](size_t bytes) -> char* {
        char* p = w;
        w += (bytes + 15) & ~(size_t)15;
        return p;
    };
    unsigned int*   t8      = (unsigned int*)alloc((size_t)N * D);          // 6.4 MB fp8 table
    _Float16*       x1h     = (_Float16*)alloc((size_t)N * D * 2);          // 12.8 MB x1 fp16
    unsigned*       buckets = (unsigned*)alloc((size_t)NBUCK * BCAP2 * 4);  // 8 MB
    _Float16*       Wt1     = (_Float16*)alloc((size_t)D * D * 2);
    _Float16*       Wt2     = (_Float16*)alloc((size_t)D * D * 2);
    unsigned short* col     = (unsigned short*)alloc((size_t)E * 2);        // 3.2 MB
    int*            bcnt    = (int*)alloc(NBUCK * 4);
    int*            row_ptr = (int*)alloc((size_t)(N + 1) * 4);
    int*            row_mid = (int*)alloc((size_t)N * 4);
    float*          dis     = (float*)alloc((size_t)N * 4);

    int npb = (N + NBUCK - 1) / NBUCK;                     // nodes per bucket (98)
    unsigned magicM = (16777216u + (unsigned)npb - 1) / (unsigned)npb;  // exact for d<186413
    int mid = N / 2;                                       // src-half split point (25000)
    int gP1 = (E + EPB - 1) / EPB;                         // 391
    int gG = (N + 63) / 64;
    int gA = (N + 7) / 8;
    int cnpb = (N + COOP_BLOCKS - 1) / COOP_BLOCKS;        // 25 nodes per coop block

    // one-time cooperative feasibility check (host-side query, graph-capture safe)
    static int coop_ok = -1;
    if (coop_ok < 0) {
        int mb1 = 0, mb2 = 0;
        hipError_t q1 = hipOccupancyMaxActiveBlocksPerMultiprocessor(&mb1, agg1_coop, 256, 0);
        hipError_t q2 = hipOccupancyMaxActiveBlocksPerMultiprocessor(&mb2, agg_head_coop, 256, 0);
        coop_ok = (q1 == hipSuccess && q2 == hipSuccess &&
                   mb1 >= COOP_BPCU && mb2 >= COOP_BPCU) ? 1 : 0;
    }
    bool use_coop = (coop_ok == 1) && (cnpb <= 32);

    prep_all_kernel<<<128, 256, 0, stream>>>(W1, Wt1, W2, Wt2, bcnt);
    bucket_pass1<<<gP1, NT, 0, stream>>>(srcp, dstp, bcnt, buckets, E, magicM);
    csr_pass2<<<NBUCK, NT, 0, stream>>>(buckets, bcnt, row_ptr, row_mid, dis, col, N, npb, E, mid);

    gemm_f32a_fp8c<<<gG, 256, 0, stream>>>(emb, Wt1, dis, t8, N);                 // hs1 fp8

    bool launched1 = false;
    if (use_coop) {
        void* a1[] = {(void*)&t8, (void*)&b1, (void*)&row_ptr, (void*)&row_mid,
                      (void*)&col, (void*)&dis, (void*)&x1h, (void*)&N, (void*)&cnpb, (void*)&mid};
        launched1 = (hipLaunchCooperativeKernel(agg1_coop, dim3(COOP_BLOCKS), dim3(256),
                                                a1, 0, stream) == hipSuccess);
    }
    if (!launched1)
        agg_fp8_kernel<<<gA, 256, 0, stream>>>(t8, b1, row_ptr, col, dis, x1h, N);

    gemm_f16a_fp8c<<<gG, 256, 0, stream>>>(x1h, Wt2, dis, t8, N);                 // hs2 fp8

    bool launched2 = false;
    if (use_coop && launched1) {
        void* a2[] = {(void*)&t8, (void*)&b2, (void*)&row_ptr, (void*)&row_mid,
                      (void*)&col, (void*)&dis, (void*)&head_w, (void*)&head_b,
                      (void*)&out, (void*)&N, (void*)&cnpb, (void*)&mid};
        launched2 = (hipLaunchCooperativeKernel(agg_head_coop, dim3(COOP_BLOCKS), dim3(256),
                                                a2, 0, stream) == hipSuccess);
    }
    if (!launched2)
        agg_head_fp8_kernel<<<gA, 256, 0, stream>>>(t8, b2, row_ptr, col, dis,
                                                    head_w, head_b, out, N);
}